// Round 15
// baseline (233.486 us; speedup 1.0000x reference)
//
#include <hip/hip_runtime.h>
#include <cstdint>
#include <cstddef>

// ---------------------------------------------------------------------------
// GenEdge R14 (resubmit — R13 bench never ran):
//   Theory: edge is L2-BW-bound (R12: 1.88 GB L2 reads @20 TB/s; R13: 2.88 GB
//   @26.7 TB/s vs ~34.5 ceiling; VALUBusy pinned ~50% at ANY occupancy).
//   edge   : block = 4 waves = 4 ADJACENT OUTPUT ROWS h0..h0+3, same 16-col
//            tile wb, FULL di 0..24. Rolling 5-slot LDS ring (60 KB) of B
//            rows: the 4 waves read 4 consecutive rows per step; 1 new row
//            (12 KB) staged per step with T14 split (loads at step top,
//            ds_write after SAD; per-step __syncthreads drains vm/lgkm).
//            L2 traffic 1.88 GB -> ~0.76 GB; ds_read imm-offset addressing.
//            Full-di: 4 accums S0,S1,T0,T1 per elem; gy=(12+mnj)*T0-T1,
//            per-di gy weight sdi in {-1,0,+1} (di=12 exactly 0 - no half
//            split, single-plane output). Grid 2256 = 94 hquads x 24 wb,
//            XCD-chunked. LDS caps 2 blocks/CU -> no launch_bounds squeeze.
//   cvt    : R11 fat-block coalesced version (unchanged).
//   combine: e=|gx|+|gy| single plane (border zeroed), block-max -> atomicMax.
//   norm   : divide by global max.
// ---------------------------------------------------------------------------

typedef _Float16 half8 __attribute__((ext_vector_type(8)));
typedef float    f32x4 __attribute__((ext_vector_type(4)));

#define HW   400
#define NP   (HW*HW)
#define CCH  128
#define W16  416                 // padded width (26 groups of 16)
#define ROWE (W16*CCH)           // 53248 f16 elements per padded row
#define PAD  12
#define IEND 388                 // interior: [12, 388)
#define LDSF 132                 // cvt: padded f32 per pixel row (128+4)
#define NSLOT 5
#define SLOTB 12288              // 3 groups x 4 KB per B-row slot

// f16 cube layout per row: [pg(26)][ks(4)][q(4)][i(16)][j(8)] elements
// offset = pg*2048 + ks*512 + q*128 + i*8 + j

// ---------------- Phase 1: convert + normalize (coalesced, fat blocks) -----
__global__ void cvt_kernel(const float* __restrict__ cube,
                           _Float16* __restrict__ c16,
                           unsigned* __restrict__ gmax) {
  __shared__ float buf[16*LDSF];   // 8448 B
  __shared__ float part[16];
  int pg = blockIdx.x;          // 0..25 (pg 25 is all-pad)
  int rb = blockIdx.y;          // 0..39 -> rows rb*10 .. rb*10+9
  int t  = threadIdx.x;         // 0..255
  if (pg == 0 && rb == 0 && t == 0) *gmax = 0u;  // every call (re-poisoned ws)
  int pa = t >> 5, oa = (t & 31)*4;
  int p  = t >> 4, k  = t & 15;
  int i  = t & 15, cb = t >> 4;
  for (int r = rb*10; r < rb*10 + 10; ++r) {
    if (pg == 25) {             // all 16 pixels are padding -> zero output
      half8 hz;
      #pragma unroll
      for (int j = 0; j < 8; ++j) hz[j] = (_Float16)0.f;
      *(half8*)(c16 + (size_t)r*ROWE + 25*2048 + t*8) = hz;
      continue;                 // block-uniform branch: barrier-safe
    }
    const float4* src4 = (const float4*)(cube + ((size_t)(r*HW + pg*16))*CCH);
    float4 fa = src4[t];
    float4 fb = src4[t + 256];
    __syncthreads();            // WAR: previous iteration's readers done
    *(float4*)&buf[pa*LDSF + oa]     = fa;
    *(float4*)&buf[(8+pa)*LDSF + oa] = fb;
    __syncthreads();
    const float4* pr = (const float4*)&buf[p*LDSF + k*8];
    float4 x0 = pr[0], x1 = pr[1];
    float ss = x0.x*x0.x + x0.y*x0.y + x0.z*x0.z + x0.w*x0.w
             + x1.x*x1.x + x1.y*x1.y + x1.z*x1.z + x1.w*x1.w;
    ss += __shfl_xor(ss, 1);
    ss += __shfl_xor(ss, 2);
    ss += __shfl_xor(ss, 4);
    ss += __shfl_xor(ss, 8);
    if (k == 0) part[p] = ss;
    __syncthreads();
    float tot = part[i];
    float sc = (tot > 0.f) ? rsqrtf(tot) : 0.f;
    const float4* vp = (const float4*)&buf[i*LDSF + cb*8];
    float4 v0 = vp[0], v1 = vp[1];
    half8 hv;
    hv[0] = (_Float16)(v0.x*sc); hv[1] = (_Float16)(v0.y*sc);
    hv[2] = (_Float16)(v0.z*sc); hv[3] = (_Float16)(v0.w*sc);
    hv[4] = (_Float16)(v1.x*sc); hv[5] = (_Float16)(v1.y*sc);
    hv[6] = (_Float16)(v1.z*sc); hv[7] = (_Float16)(v1.w*sc);
    *(half8*)(c16 + (size_t)r*ROWE + pg*2048 + t*8) = hv;
  }
}

// ---------------- Phase 2: LDS-shared banded MFMA + SAD -------------------
__global__ __launch_bounds__(256) void edge_kernel(
    const _Float16* __restrict__ c16,
    float* __restrict__ gxp, float* __restrict__ gyp) {
  __shared__ char bs[NSLOT*SLOTB];       // 60 KB: 5-row ring of B rows
  // 2256 blocks = 8 XCDs x 282; g = hq*24 + wb (wb fastest: B-row L2 reuse
  // across adjacent-wb blocks in the same band).
  const int id = blockIdx.x;
  const int g  = (id & 7)*282 + (id >> 3);
  const int hq = g / 24;                 // 0..93
  const int wb = g - hq*24;              // 0..23
  const int h0 = PAD + 4*hq;             // block's first output row
  const int wv = threadIdx.x >> 6;       // wave 0..3 -> row h0+wv
  const int h  = h0 + wv;                // 12..387
  const int l  = threadIdx.x & 63;
  const int c  = l & 15, q = l >> 4;
  const int w0 = PAD + 16*wb;            // first center col of tile
  // B groups staged per row: wb, wb+1, wb+2 (covers dj window of 16 cols)

  // A-frags: center pixels w0..w0+15 of row h.  A[m=lane&15][k=q*8+j]
  half8 A[4];
  {
    int px = w0 + c;                     // <= 395 < 400
    const _Float16* pA = c16 + (size_t)h*ROWE + (px >> 4)*2048 + q*128 + (px & 15)*8;
    #pragma unroll
    for (int ks = 0; ks < 4; ++ks)
      A[ks] = *(const half8*)(pA + ks*512);
  }

  const float cq = (float)(c - 4*q);     // dj-12 = 16d - 12 - rr + (c-4q)

  // factored accumulators (full-di):
  //   gx = p*S0 + sgn(p)*S1 ;  gy = (12+mnj)*T0 - T1
  float S0[3][4], S1[3][4], T0[3][4], T1[3][4];
  #pragma unroll
  for (int d = 0; d < 3; ++d)
    #pragma unroll
    for (int rr = 0; rr < 4; ++rr) {
      S0[d][rr] = 0.f; S1[d][rr] = 0.f; T0[d][rr] = 0.f; T1[d][rr] = 0.f;
    }

  const f32x4 z4 = {0.f, 0.f, 0.f, 0.f};

  // ---- prologue: stage rows s=0..3 (r = h0-12+s) into slots 0..3 ----
  // 12 KB/row, 256 threads x 48 B: wave wv covers bytes [wv*3072, wv*3072+3072)
  #pragma unroll
  for (int s = 0; s < 4; ++s) {
    const _Float16* src = c16 + (size_t)(h0 - 12 + s)*ROWE + wb*2048
                        + wv*1536 + (size_t)l*8;
    char* dst = &bs[s*SLOTB + wv*3072 + l*16];
    #pragma unroll
    for (int k = 0; k < 3; ++k)
      *(half8*)(dst + k*1024) = *(const half8*)(src + k*512);
  }
  __syncthreads();

  #pragma unroll 1
  for (int di = 0; di < 25; ++di) {
    // ---- T14 stage-load: issue global loads for row r = h0+di-8 now ----
    half8 st0, st1, st2;
    if (di < 24) {
      const _Float16* src = c16 + (size_t)(h0 + di - 8)*ROWE + wb*2048
                          + wv*1536 + (size_t)l*8;
      st0 = *(const half8*)(src);
      st1 = *(const half8*)(src + 512);
      st2 = *(const half8*)(src + 1024);
    }

    // ---- MFMA phase: read B frags from my row's slot ----
    const char* bsw = &bs[((di + wv) % NSLOT)*SLOTB];
    f32x4 acc[3];
    #pragma unroll
    for (int ks = 0; ks < 4; ++ks) {
      half8 B0 = *(const half8*)(bsw + 0*4096 + ks*1024 + l*16);
      half8 B1 = *(const half8*)(bsw + 1*4096 + ks*1024 + l*16);
      half8 B2 = *(const half8*)(bsw + 2*4096 + ks*1024 + l*16);
      if (ks == 0) {
        acc[0] = __builtin_amdgcn_mfma_f32_16x16x32_f16(A[0], B0, z4, 0,0,0);
        acc[1] = __builtin_amdgcn_mfma_f32_16x16x32_f16(A[0], B1, z4, 0,0,0);
        acc[2] = __builtin_amdgcn_mfma_f32_16x16x32_f16(A[0], B2, z4, 0,0,0);
      } else {
        acc[0] = __builtin_amdgcn_mfma_f32_16x16x32_f16(A[ks], B0, acc[0], 0,0,0);
        acc[1] = __builtin_amdgcn_mfma_f32_16x16x32_f16(A[ks], B1, acc[1], 0,0,0);
        acc[2] = __builtin_amdgcn_mfma_f32_16x16x32_f16(A[ks], B2, acc[2], 0,0,0);
      }
    }

    // ---- SAD phase: 4-accumulator factored weighting ----
    // ii = 12-|di-12|; sdi = sign(di-12) (0 at di=12 -> gy weight exactly 0)
    const float ii  = (float)((di <= 12) ? di : 24 - di);
    const float sdi = (float)((di > 12) - (di < 12));
    const float wt1 = sdi * ii;

    #pragma unroll
    for (int d = 0; d < 3; ++d)
      #pragma unroll
      for (int rr = 0; rr < 4; ++rr) {
        float x  = acc[d][rr];                       // cos in [0, 1+eps)
        float sq = __builtin_amdgcn_sqrtf(fmaxf(1.0f - x, 0.0f));
        float pl = fmaf(x, -0.0187292994f, 0.0742610134f);
        pl = fmaf(pl, x, -0.2121143967f);
        pl = fmaf(pl, x,  1.5707287572f);
        float sad = sq * pl;                         // acos(x), |err|<7e-5
        S0[d][rr] += sad;
        S1[d][rr] = fmaf(sad, ii,  S1[d][rr]);
        T0[d][rr] = fmaf(sad, sdi, T0[d][rr]);
        T1[d][rr] = fmaf(sad, wt1, T1[d][rr]);
      }

    // ---- T14 stage-write: loads have landed under the SAD chain ----
    // writer slot (di+4)%5 is disjoint from reader slots (di..di+3)%5
    if (di < 24) {
      char* dst = &bs[((di + 4) % NSLOT)*SLOTB + wv*3072 + l*16];
      *(half8*)(dst)        = st0;
      *(half8*)(dst + 1024) = st1;
      *(half8*)(dst + 2048) = st2;
    }
    __syncthreads();   // drains vm/lgkm: staged row visible to all next step
  }

  // epilogue: apply di-invariant weights once.
  float gx[4], gy[4];
  #pragma unroll
  for (int rr = 0; rr < 4; ++rr) { gx[rr] = 0.f; gy[rr] = 0.f; }

  #pragma unroll
  for (int d = 0; d < 3; ++d)
    #pragma unroll
    for (int rr = 0; rr < 4; ++rr) {
      float p   = cq + (float)(16*d - 12 - rr);   // dj - 12 (integer)
      float ap  = fabsf(p);
      float mnj = 12.0f - ap;                     // >=0 iff |dj-12|<=12
      bool  ok  = mnj >= 0.0f;
      float sg  = fminf(fmaxf(p, -1.0f), 1.0f);   // sgn(p)
      float wy  = 12.0f + mnj;
      gx[rr] += ok ? fmaf(sg, S1[d][rr], p*S0[d][rr]) : 0.0f;
      gy[rr] += ok ? fmaf(wy, T0[d][rr], -T1[d][rr]) : 0.0f;
    }

  // reduce over c (lane bits 0..3); writer lanes c == rr store
  const int hoff = h*HW;
  #pragma unroll
  for (int rr = 0; rr < 4; ++rr) {
    float sgx = gx[rr], sgy = gy[rr];
    #pragma unroll
    for (int m = 1; m < 16; m <<= 1) {
      sgx += __shfl_xor(sgx, m);
      sgy += __shfl_xor(sgy, m);
    }
    if (c == rr) {
      int w = w0 + 4*q + rr;             // <= 395, disjoint across waves
      gxp[hoff + w] = sgx;
      gyp[hoff + w] = sgy;
    }
  }
}

// ---------------- Phase 3a: combine + global max ----------------
__global__ void combine_kernel(float* __restrict__ gxp,
                               const float* __restrict__ gyp,
                               unsigned* __restrict__ gmax) {
  __shared__ float wm[4];
  int idx = blockIdx.x*256 + threadIdx.x;      // 625*256 = NP exactly
  int hh = idx / HW;
  int ww = idx - hh*HW;
  float e = 0.f;
  if (hh >= PAD && hh < IEND && ww >= PAD && ww < IEND)
    e = fabsf(gxp[idx]) + fabsf(gyp[idx]);
  gxp[idx] = e;                                // edge buffer aliases gxp
  float m = e;
  #pragma unroll
  for (int off = 1; off < 64; off <<= 1) m = fmaxf(m, __shfl_xor(m, off));
  if ((threadIdx.x & 63) == 0) wm[threadIdx.x >> 6] = m;
  __syncthreads();
  if (threadIdx.x == 0) {
    float mm = fmaxf(fmaxf(wm[0], wm[1]), fmaxf(wm[2], wm[3]));
    atomicMax(gmax, __float_as_uint(mm));      // e >= 0: uint order ok
  }
}

// ---------------- Phase 3b: normalize ----------------
__global__ void norm_kernel(const float* __restrict__ edge,
                            const unsigned* __restrict__ gmax,
                            float* __restrict__ out) {
  int idx = blockIdx.x*256 + threadIdx.x;
  float mv = __uint_as_float(*gmax);
  out[idx] = edge[idx] / mv;                   // border already 0
}

// ---------------- launch ----------------
extern "C" void kernel_launch(void* const* d_in, const int* in_sizes, int n_in,
                              void* d_out, int out_size, void* d_ws, size_t ws_size,
                              hipStream_t stream) {
  const float* cube = (const float*)d_in[0];   // (1,400,400,128) f32
  char* ws = (char*)d_ws;
  _Float16* c16  = (_Float16*)(ws);                     // 42,598,400 B
  float*    gxp  = (float*)(ws + 42598400);             // NP floats
  float*    gyp  = (float*)(ws + 42598400 + 4*NP);      // NP floats
  unsigned* gmax = (unsigned*)(ws + 42598400 + 8*NP);   // 4 B (~43.9 MB total)

  cvt_kernel<<<dim3(26, 40), 256, 0, stream>>>(cube, c16, gmax);
  edge_kernel<<<2256, 256, 0, stream>>>(c16, gxp, gyp);
  combine_kernel<<<NP/256, 256, 0, stream>>>(gxp, gyp, gmax);
  norm_kernel<<<NP/256, 256, 0, stream>>>(gxp, gmax, (float*)d_out);
}

// Round 17
// 225.562 us; speedup vs baseline: 1.0351x; 1.0351x over previous
//
#include <hip/hip_runtime.h>
#include <cstdint>
#include <cstddef>

// ---------------------------------------------------------------------------
// GenEdge R16 (resubmit — R15 bench never ran) — split-edge probe:
//   edge   : EXACT R12 core (best measured: 94.8 us; 32-col waves, 4-wave WG
//            same row+half, adjacent wb, B-prefetch pipeline, factored
//            weighting, plain stores), but launched as TWO dispatches
//            (half=0,1; 1128 blocks each, 8x141 XCD-chunked). Each half
//            ~47-55 us -> if cvt is the ~110 us gap sink it MUST surface in
//            rocprof top-5 with counters; if absent, gap is harness floor.
//   cvt    : R11 fat-block coalesced version (unchanged).
//   combine: sum halves, e=|gx|+|gy| (border zeroed), block-max -> atomicMax.
//   norm   : divide by global max.
//   Refuted so far: occupancy (VALUBusy ~50% at 18-38% occ), L2-BW (R14 LDS
//   cut traffic 2.5x, got slower via 25 per-step barriers).
// ---------------------------------------------------------------------------

typedef _Float16 half8 __attribute__((ext_vector_type(8)));
typedef float    f32x4 __attribute__((ext_vector_type(4)));

#define HW   400
#define NP   (HW*HW)
#define CCH  128
#define W16  416                 // padded width (26 groups of 16)
#define ROWE (W16*CCH)           // 53248 f16 elements per padded row
#define PAD  12
#define IEND 388                 // interior: [12, 388)
#define LDSF 132                 // cvt: padded f32 per pixel row (128+4)

// f16 cube layout per row: [pg(26)][ks(4)][q(4)][i(16)][j(8)] elements
// offset = pg*2048 + ks*512 + q*128 + i*8 + j

// ---------------- Phase 1: convert + normalize (coalesced, fat blocks) -----
__global__ void cvt_kernel(const float* __restrict__ cube,
                           _Float16* __restrict__ c16,
                           unsigned* __restrict__ gmax) {
  __shared__ float buf[16*LDSF];   // 8448 B
  __shared__ float part[16];
  int pg = blockIdx.x;          // 0..25 (pg 25 is all-pad)
  int rb = blockIdx.y;          // 0..39 -> rows rb*10 .. rb*10+9
  int t  = threadIdx.x;         // 0..255
  if (pg == 0 && rb == 0 && t == 0) *gmax = 0u;  // every call (re-poisoned ws)
  int pa = t >> 5, oa = (t & 31)*4;
  int p  = t >> 4, k  = t & 15;
  int i  = t & 15, cb = t >> 4;
  for (int r = rb*10; r < rb*10 + 10; ++r) {
    if (pg == 25) {             // all 16 pixels are padding -> zero output
      half8 hz;
      #pragma unroll
      for (int j = 0; j < 8; ++j) hz[j] = (_Float16)0.f;
      *(half8*)(c16 + (size_t)r*ROWE + 25*2048 + t*8) = hz;
      continue;                 // block-uniform branch: barrier-safe
    }
    // coalesced read: 2048 consecutive floats (16 pixels x 128 ch)
    const float4* src4 = (const float4*)(cube + ((size_t)(r*HW + pg*16))*CCH);
    float4 fa = src4[t];
    float4 fb = src4[t + 256];
    __syncthreads();            // WAR: previous iteration's readers done
    *(float4*)&buf[pa*LDSF + oa]     = fa;
    *(float4*)&buf[(8+pa)*LDSF + oa] = fb;
    __syncthreads();
    const float4* pr = (const float4*)&buf[p*LDSF + k*8];
    float4 x0 = pr[0], x1 = pr[1];
    float ss = x0.x*x0.x + x0.y*x0.y + x0.z*x0.z + x0.w*x0.w
             + x1.x*x1.x + x1.y*x1.y + x1.z*x1.z + x1.w*x1.w;
    ss += __shfl_xor(ss, 1);
    ss += __shfl_xor(ss, 2);
    ss += __shfl_xor(ss, 4);
    ss += __shfl_xor(ss, 8);
    if (k == 0) part[p] = ss;
    __syncthreads();
    float tot = part[i];
    float sc = (tot > 0.f) ? rsqrtf(tot) : 0.f;
    const float4* vp = (const float4*)&buf[i*LDSF + cb*8];
    float4 v0 = vp[0], v1 = vp[1];
    half8 hv;
    hv[0] = (_Float16)(v0.x*sc); hv[1] = (_Float16)(v0.y*sc);
    hv[2] = (_Float16)(v0.z*sc); hv[3] = (_Float16)(v0.w*sc);
    hv[4] = (_Float16)(v1.x*sc); hv[5] = (_Float16)(v1.y*sc);
    hv[6] = (_Float16)(v1.z*sc); hv[7] = (_Float16)(v1.w*sc);
    *(half8*)(c16 + (size_t)r*ROWE + pg*2048 + t*8) = hv;
  }
}

// ---------------- Phase 2: banded MFMA + SAD partials (pipelined) ----------
__global__ __launch_bounds__(256, 2) void edge_kernel(
    const _Float16* __restrict__ c16,
    float* __restrict__ gxp, float* __restrict__ gyp, const int half) {
  // 1128 blocks = 8 XCDs x 141 (47 rows x 3 wbq per XCD, contiguous band).
  // Block: 4 waves, wave wv -> wb = wbq*4 + wv, all SAME row h; half fixed.
  const int id  = blockIdx.x;
  const int g   = (id & 7)*141 + (id >> 3);
  const int row = g / 3;                 // 0..375
  const int wbq = g - row*3;             // 0..2
  const int h   = row + PAD;             // 12..387
  const int wv  = threadIdx.x >> 6;      // wave 0..3
  const int wb  = wbq*4 + wv;            // 0..11
  const int l   = threadIdx.x & 63;
  const int c   = l & 15, q = l >> 4;
  const int w0  = PAD + 32*wb;
  const int g0  = 2*wb;                  // first B pixel-group

  // A-frags: center pixels of row h.  A[m=lane&15][k=q*8+j]
  half8 A[2][4];
  #pragma unroll
  for (int t = 0; t < 2; ++t) {
    int px = w0 + 16*t + c;              // <= 395 < 400
    const _Float16* p = c16 + (size_t)h*ROWE + (px >> 4)*2048 + q*128 + (px & 15)*8;
    #pragma unroll
    for (int ks = 0; ks < 4; ++ks)
      A[t][ks] = *(const half8*)(p + ks*512);
  }

  const float cq = (float)(c - 4*q);     // dj-12 = 16d - 12 - rr + (c-4q)

  // factored accumulators: S0 = sum w*sad, S1 = sum w*sad*ii
  float S0[2][3][4], S1[2][3][4];
  #pragma unroll
  for (int t = 0; t < 2; ++t)
    #pragma unroll
    for (int d = 0; d < 3; ++d)
      #pragma unroll
      for (int rr = 0; rr < 4; ++rr) { S0[t][d][rr] = 0.f; S1[t][d][rr] = 0.f; }

  const f32x4 z4 = {0.f, 0.f, 0.f, 0.f};
  const _Float16* bBase = c16 + g0*2048 + (size_t)l*8;
  // di=12 belongs to BOTH halves at weight 0.5.
  const int diLo = half ? 12 : 0;
  const int diHi = half ? 25 : 13;

  // B frags for the CURRENT di, preloaded; refilled for di+1 after the MFMA
  // phase and before the SAD chain (software pipeline).
  half8 B[4][4];                         // [group][ks], 64 VGPRs
  {
    const _Float16* rowB = bBase + (size_t)(h + diLo - PAD)*ROWE;
    #pragma unroll
    for (int gg = 0; gg < 4; ++gg)
      #pragma unroll
      for (int ks = 0; ks < 4; ++ks)
        B[gg][ks] = *(const half8*)(rowB + gg*2048 + ks*512);
  }

  #pragma unroll 1
  for (int di = diLo; di < diHi; ++di) {
    // ---- MFMA phase (consumes B) ----
    f32x4 acc[2][3];
    #pragma unroll
    for (int ks = 0; ks < 4; ++ks) {
      if (ks == 0) {
        acc[0][0] = __builtin_amdgcn_mfma_f32_16x16x32_f16(A[0][0], B[0][0], z4, 0,0,0);
        acc[0][1] = __builtin_amdgcn_mfma_f32_16x16x32_f16(A[0][0], B[1][0], z4, 0,0,0);
        acc[0][2] = __builtin_amdgcn_mfma_f32_16x16x32_f16(A[0][0], B[2][0], z4, 0,0,0);
        acc[1][0] = __builtin_amdgcn_mfma_f32_16x16x32_f16(A[1][0], B[1][0], z4, 0,0,0);
        acc[1][1] = __builtin_amdgcn_mfma_f32_16x16x32_f16(A[1][0], B[2][0], z4, 0,0,0);
        acc[1][2] = __builtin_amdgcn_mfma_f32_16x16x32_f16(A[1][0], B[3][0], z4, 0,0,0);
      } else {
        acc[0][0] = __builtin_amdgcn_mfma_f32_16x16x32_f16(A[0][ks], B[0][ks], acc[0][0], 0,0,0);
        acc[0][1] = __builtin_amdgcn_mfma_f32_16x16x32_f16(A[0][ks], B[1][ks], acc[0][1], 0,0,0);
        acc[0][2] = __builtin_amdgcn_mfma_f32_16x16x32_f16(A[0][ks], B[2][ks], acc[0][2], 0,0,0);
        acc[1][0] = __builtin_amdgcn_mfma_f32_16x16x32_f16(A[1][ks], B[1][ks], acc[1][0], 0,0,0);
        acc[1][1] = __builtin_amdgcn_mfma_f32_16x16x32_f16(A[1][ks], B[2][ks], acc[1][1], 0,0,0);
        acc[1][2] = __builtin_amdgcn_mfma_f32_16x16x32_f16(A[1][ks], B[3][ks], acc[1][2], 0,0,0);
      }
    }

    // ---- prefetch B for di+1 (issued before the SAD chain; its ~400-cyc
    //      VALU tail covers the ~200-cyc L2 latency) ----
    if (di + 1 < diHi) {
      const _Float16* rowB = bBase + (size_t)(h + di + 1 - PAD)*ROWE;
      #pragma unroll
      for (int gg = 0; gg < 4; ++gg)
        #pragma unroll
        for (int ks = 0; ks < 4; ++ks)
          B[gg][ks] = *(const half8*)(rowB + gg*2048 + ks*512);
    }

    // ---- SAD phase (consumes acc; per-di scalars only) ----
    const float ii  = (float)((di <= 12) ? di : 24 - di);
    const float w0s = (di == 12) ? 0.5f : 1.0f;
    const float w1s = w0s * ii;

    #pragma unroll
    for (int t = 0; t < 2; ++t)
      #pragma unroll
      for (int d = 0; d < 3; ++d)
        #pragma unroll
        for (int rr = 0; rr < 4; ++rr) {
          float x  = acc[t][d][rr];                    // cos in [0, 1+eps)
          float sq = __builtin_amdgcn_sqrtf(fmaxf(1.0f - x, 0.0f));
          float pl = fmaf(x, -0.0187292994f, 0.0742610134f);
          pl = fmaf(pl, x, -0.2121143967f);
          pl = fmaf(pl, x,  1.5707287572f);
          float sad = sq * pl;                         // acos(x), |err|<7e-5
          S0[t][d][rr] = fmaf(sad, w0s, S0[t][d][rr]);
          S1[t][d][rr] = fmaf(sad, w1s, S1[t][d][rr]);
        }
  }

  // epilogue: apply di-invariant weights once.
  //   kx = p + sg*ii            -> gx = p*S0 + sg*S1
  //   ky = s_h*(12 + mnj - ii)  -> gy = s_h*((12+mnj)*S0 - S1)
  const float s_h = half ? 1.0f : -1.0f;
  float gx[2][4], gy[2][4];
  #pragma unroll
  for (int t = 0; t < 2; ++t)
    #pragma unroll
    for (int rr = 0; rr < 4; ++rr) { gx[t][rr] = 0.f; gy[t][rr] = 0.f; }

  #pragma unroll
  for (int d = 0; d < 3; ++d)
    #pragma unroll
    for (int rr = 0; rr < 4; ++rr) {
      float p   = cq + (float)(16*d - 12 - rr);   // dj - 12 (integer)
      float ap  = fabsf(p);
      float mnj = 12.0f - ap;                     // >=0 iff |dj-12|<=12
      bool  ok  = mnj >= 0.0f;
      float sg  = fminf(fmaxf(p, -1.0f), 1.0f);   // sgn(p)
      float wy  = 12.0f + mnj;
      #pragma unroll
      for (int t = 0; t < 2; ++t) {
        float s0 = S0[t][d][rr], s1 = S1[t][d][rr];
        float gxc = ok ? fmaf(sg, s1, p*s0) : 0.0f;
        float gyc = ok ? s_h*fmaf(wy, s0, -s1) : 0.0f;
        gx[t][rr] += gxc;
        gy[t][rr] += gyc;
      }
    }

  // reduce over c (lane bits 0..3); writer lanes c == rr store partials
  const int hoff = half*NP + h*HW;
  #pragma unroll
  for (int t = 0; t < 2; ++t)
    #pragma unroll
    for (int rr = 0; rr < 4; ++rr) {
      float sgx = gx[t][rr], sgy = gy[t][rr];
      #pragma unroll
      for (int m = 1; m < 16; m <<= 1) {
        sgx += __shfl_xor(sgx, m);
        sgy += __shfl_xor(sgy, m);
      }
      if (c == rr) {
        int w = w0 + 16*t + 4*q + rr;    // <= 395, disjoint across waves
        gxp[hoff + w] = sgx;
        gyp[hoff + w] = sgy;
      }
    }
}

// ---------------- Phase 3a: combine halves + global max ----------------
__global__ void combine_kernel(float* __restrict__ gxp,
                               const float* __restrict__ gyp,
                               unsigned* __restrict__ gmax) {
  __shared__ float wm[4];
  int idx = blockIdx.x*256 + threadIdx.x;      // 625*256 = NP exactly
  int hh = idx / HW;
  int ww = idx - hh*HW;
  float e = 0.f;
  if (hh >= PAD && hh < IEND && ww >= PAD && ww < IEND)
    e = fabsf(gxp[idx] + gxp[NP + idx]) + fabsf(gyp[idx] + gyp[NP + idx]);
  gxp[idx] = e;                                // edge buffer aliases gxp[0]
  float m = e;
  #pragma unroll
  for (int off = 1; off < 64; off <<= 1) m = fmaxf(m, __shfl_xor(m, off));
  if ((threadIdx.x & 63) == 0) wm[threadIdx.x >> 6] = m;
  __syncthreads();
  if (threadIdx.x == 0) {
    float mm = fmaxf(fmaxf(wm[0], wm[1]), fmaxf(wm[2], wm[3]));
    atomicMax(gmax, __float_as_uint(mm));      // e >= 0: uint order ok
  }
}

// ---------------- Phase 3b: normalize ----------------
__global__ void norm_kernel(const float* __restrict__ edge,
                            const unsigned* __restrict__ gmax,
                            float* __restrict__ out) {
  int idx = blockIdx.x*256 + threadIdx.x;
  float mv = __uint_as_float(*gmax);
  out[idx] = edge[idx] / mv;                   // border already 0
}

// ---------------- launch ----------------
extern "C" void kernel_launch(void* const* d_in, const int* in_sizes, int n_in,
                              void* d_out, int out_size, void* d_ws, size_t ws_size,
                              hipStream_t stream) {
  const float* cube = (const float*)d_in[0];   // (1,400,400,128) f32
  char* ws = (char*)d_ws;
  _Float16* c16  = (_Float16*)(ws);                     // 42,598,400 B
  float*    gxp  = (float*)(ws + 42598400);             // 2*NP floats
  float*    gyp  = (float*)(ws + 42598400 + 8*NP);      // 2*NP floats
  unsigned* gmax = (unsigned*)(ws + 42598400 + 16*NP);  // 4 B  (~45.2 MB total)

  cvt_kernel<<<dim3(26, 40), 256, 0, stream>>>(cube, c16, gmax);
  edge_kernel<<<1128, 256, 0, stream>>>(c16, gxp, gyp, 0);
  edge_kernel<<<1128, 256, 0, stream>>>(c16, gxp, gyp, 1);
  combine_kernel<<<NP/256, 256, 0, stream>>>(gxp, gyp, gmax);
  norm_kernel<<<NP/256, 256, 0, stream>>>(gxp, gmax, (float*)d_out);
}